// Round 4
// baseline (624.258 us; speedup 1.0000x reference)
//
#include <hip/hip_runtime.h>
#include <hip/hip_bf16.h>

typedef __bf16 bf16x8 __attribute__((ext_vector_type(8)));
typedef float  f32x4  __attribute__((ext_vector_type(4)));

// ---------- helpers ----------
static __device__ __forceinline__ unsigned short f2bf(float f) {
  unsigned int u = __float_as_uint(f);
  u += 0x7FFFu + ((u >> 16) & 1u);   // round-to-nearest-even
  return (unsigned short)(u >> 16);
}

static __device__ __forceinline__ void gl_lds16(const void* g, void* l) {
  __builtin_amdgcn_global_load_lds(
      (const __attribute__((address_space(1))) void*)g,
      (__attribute__((address_space(3))) void*)l,
      16, 0, 0);
}

// ---------- cast x: f32 -> bf16 ----------
__global__ __launch_bounds__(256) void cast_f32_bf16(
    const float* __restrict__ in, unsigned short* __restrict__ out, int n) {
  int i = (blockIdx.x * 256 + threadIdx.x) * 4;
  const int stride = gridDim.x * 256 * 4;
  for (; i < n; i += stride) {
    float4 f = *(const float4*)(in + i);
    ushort4 o;
    o.x = f2bf(f.x); o.y = f2bf(f.y); o.z = f2bf(f.z); o.w = f2bf(f.w);
    *(ushort4*)(out + i) = o;
  }
}

// ---------- transpose-cast W (1024x1024): wt[n][k] = w[k][n], f32 -> bf16 ----------
__global__ __launch_bounds__(256) void transpose_cast_w(
    const float* __restrict__ w, unsigned short* __restrict__ wt) {
  __shared__ float tile[16][17];
  const int tx = threadIdx.x & 15, ty = threadIdx.x >> 4;
  const int bx = blockIdx.x * 16, by = blockIdx.y * 16;
  tile[ty][tx] = w[(size_t)(by + ty) * 1024 + bx + tx];
  __syncthreads();
  wt[(size_t)(bx + ty) * 1024 + by + tx] = f2bf(tile[tx][ty]);
}

// ---------- 256x256-tile bf16 MFMA GEMM, K-tile pairs (BK=64), 8-phase-style ----------
// B given transposed ([N][K]). 4 LDS slots of BK=32 (A 16KB | B 16KB each);
// pair p occupies slots {0,1} or {2,3} (parity alternates). Layout per slot:
// [kq 0..3][row 0..255][16B] -- conflict-free ds_read_b128 AND linear
// global_load_lds dest (verified: SQ_LDS_BANK_CONFLICT == 0 in r2/r3).
// Per pair (2 K-tiles, 64 K): 4 phases x {asm ds_read subtile | gl_lds stage |
// s_barrier | lgkmcnt(0)+sched_barrier | setprio(1) 16 MFMA setprio(0) | s_barrier}.
// Reads per phase: 12 / 4 / 8 / 0. Stages for pair p+2: phase3 = B(t0') x2
// (B regions freed at ph2-end barrier), phase4 = B(t1') x2 + A(t0',t1') x4
// (A regions freed at ph3-end barrier). vmcnt(8) only at pair top (2 pairs
// in flight, never drained mid-loop); vmcnt(0) at last pair.
// All ds_reads are inline asm WITHOUT memory clobber so the compiler cannot
// alias them against the gl_lds staging writes and insert vmcnt drains
// (r3's 17% MfmaUtil failure). Waits are fully manual (rule #18 fences).
// MODE 2: C f32 [z*cstride + row*ldc + col]
// MODE 3: fused-QKV split write (Cv = qb base; kb = +16Mi elems, vt = +32Mi)
template <int MODE>
__global__ __launch_bounds__(512, 2) void gemm256(
    const unsigned short* __restrict__ A, int lda, size_t astride,
    const unsigned short* __restrict__ B, int ldb, size_t bstride,
    int K, void* __restrict__ Cv, int ldc, size_t cstride) {
  __shared__ __align__(16) unsigned char lds[131072];

  const unsigned d2 = blockIdx.x + gridDim.x * blockIdx.y;
  const unsigned ty = d2 % gridDim.y;
  const unsigned tx = d2 / gridDim.y;
  const int bm0 = ty * 256;
  const int bn0 = tx * 256;
  A += (size_t)blockIdx.z * astride;
  B += (size_t)blockIdx.z * bstride;

  const int tid = threadIdx.x;
  const int wid = tid >> 6, lane = tid & 63;
  const int wr = wid >> 2, wc = wid & 3;        // wave grid 2(M) x 4(N)
  const int l15 = lane & 15, kq = lane >> 4;

  // staging source: chunk (wid*64+lane) -> kq_g = wid>>2 (+2 for j=1), row = (wid&3)*64+lane
  const int srow = ((wid & 3) << 6) + lane;
  const int skq0 = wid >> 2;
  const size_t aoff0 = (size_t)(bm0 + srow) * lda + skq0 * 8;
  const size_t aoff1 = aoff0 + 16;
  const size_t boff0 = (size_t)(bn0 + srow) * ldb + skq0 * 8;
  const size_t boff1 = boff0 + 16;
  const int ldst0 = wid * 1024;          // wave-uniform LDS byte offset (j=0)
  const int ldst1 = 8192 + wid * 1024;   // j=1

  // LDS byte-address bases for asm ds_read_b128
  const unsigned ldsbase =
      (unsigned)(unsigned long long)(__attribute__((address_space(3))) unsigned char*)lds;
  const unsigned aA = ldsbase + kq * 4096 + (wr * 128 + l15) * 16;
  const unsigned aB = ldsbase + 16384 + kq * 4096 + (wc * 64 + l15) * 16;

#define SLOT(t) ((unsigned)((t) & 3) * 32768u)
#define STAGE_A(t, j) gl_lds16(A + ((j) ? aoff1 : aoff0) + (size_t)(t) * 32, \
                               lds + SLOT(t) + ((j) ? ldst1 : ldst0))
#define STAGE_B(t, j) gl_lds16(B + ((j) ? boff1 : boff0) + (size_t)(t) * 32, \
                               lds + SLOT(t) + 16384 + ((j) ? ldst1 : ldst0))
#define DSR(dst, addr) asm volatile("ds_read_b128 %0, %1" : "=v"(dst) : "v"(addr))

  f32x4 acc[8][4] = {};
  bf16x8 af0[4], af1[4], bg0[2], bg1[2], bh0[2], bh1[2];

  const int npair = K >> 6;   // K % 64 == 0 (1024 or 2048 here)
  // prologue: stage pairs 0 and 1 (16 loads)
#pragma unroll
  for (int t = 0; t < 4; ++t) { STAGE_A(t, 0); STAGE_A(t, 1); STAGE_B(t, 0); STAGE_B(t, 1); }

  for (int p = 0; p < npair; ++p) {
    const int t0 = 2 * p, t1 = 2 * p + 1;
    const unsigned s0 = SLOT(t0), s1 = SLOT(t1);
    if (p < npair - 1) asm volatile("s_waitcnt vmcnt(8)" ::: "memory");
    else               asm volatile("s_waitcnt vmcnt(0)" ::: "memory");
    __builtin_amdgcn_s_barrier();   // all waves' pair-p stages landed

    // ---------- phase 1: quadrant (mi 0-3, ni 0-1) -- 12 ds_reads ----------
#pragma unroll
    for (int mi = 0; mi < 4; ++mi) DSR(af0[mi], s0 + aA + mi * 256);
#pragma unroll
    for (int mi = 0; mi < 4; ++mi) DSR(af1[mi], s1 + aA + mi * 256);
#pragma unroll
    for (int ni = 0; ni < 2; ++ni) { DSR(bg0[ni], s0 + aB + ni * 256); DSR(bg1[ni], s1 + aB + ni * 256); }
    asm volatile("s_waitcnt lgkmcnt(8)" ::: "memory");
    __builtin_amdgcn_s_barrier();
    asm volatile("s_waitcnt lgkmcnt(0)" ::: "memory");
    __builtin_amdgcn_sched_barrier(0);
    __builtin_amdgcn_s_setprio(1);
#pragma unroll
    for (int mi = 0; mi < 4; ++mi)
#pragma unroll
      for (int ni = 0; ni < 2; ++ni)
        acc[mi][ni] = __builtin_amdgcn_mfma_f32_16x16x32_bf16(af0[mi], bg0[ni], acc[mi][ni], 0, 0, 0);
#pragma unroll
    for (int mi = 0; mi < 4; ++mi)
#pragma unroll
      for (int ni = 0; ni < 2; ++ni)
        acc[mi][ni] = __builtin_amdgcn_mfma_f32_16x16x32_bf16(af1[mi], bg1[ni], acc[mi][ni], 0, 0, 0);
    __builtin_amdgcn_s_setprio(0);
    __builtin_amdgcn_s_barrier();

    // ---------- phase 2: quadrant (mi 0-3, ni 2-3) -- 4 ds_reads ----------
    DSR(bh0[0], s0 + aB + 2 * 256); DSR(bh0[1], s0 + aB + 3 * 256);
    DSR(bh1[0], s1 + aB + 2 * 256); DSR(bh1[1], s1 + aB + 3 * 256);
    __builtin_amdgcn_s_barrier();
    asm volatile("s_waitcnt lgkmcnt(0)" ::: "memory");
    __builtin_amdgcn_sched_barrier(0);
    __builtin_amdgcn_s_setprio(1);
#pragma unroll
    for (int mi = 0; mi < 4; ++mi)
#pragma unroll
      for (int ni = 0; ni < 2; ++ni)
        acc[mi][ni + 2] = __builtin_amdgcn_mfma_f32_16x16x32_bf16(af0[mi], bh0[ni], acc[mi][ni + 2], 0, 0, 0);
#pragma unroll
    for (int mi = 0; mi < 4; ++mi)
#pragma unroll
      for (int ni = 0; ni < 2; ++ni)
        acc[mi][ni + 2] = __builtin_amdgcn_mfma_f32_16x16x32_bf16(af1[mi], bh1[ni], acc[mi][ni + 2], 0, 0, 0);
    __builtin_amdgcn_s_setprio(0);
    __builtin_amdgcn_s_barrier();

    // ---------- phase 3: quadrant (mi 4-7, ni 2-3) -- 8 ds_reads + stage B' ----------
#pragma unroll
    for (int mi = 0; mi < 4; ++mi) DSR(af0[mi], s0 + aA + (mi + 4) * 256);
#pragma unroll
    for (int mi = 0; mi < 4; ++mi) DSR(af1[mi], s1 + aA + (mi + 4) * 256);
    if (p + 2 < npair) { STAGE_B(t0 + 4, 0); STAGE_B(t0 + 4, 1); }  // B slot freed at ph2 barrier
    __builtin_amdgcn_s_barrier();
    asm volatile("s_waitcnt lgkmcnt(0)" ::: "memory");
    __builtin_amdgcn_sched_barrier(0);
    __builtin_amdgcn_s_setprio(1);
#pragma unroll
    for (int mi = 0; mi < 4; ++mi)
#pragma unroll
      for (int ni = 0; ni < 2; ++ni)
        acc[mi + 4][ni + 2] = __builtin_amdgcn_mfma_f32_16x16x32_bf16(af0[mi], bh0[ni], acc[mi + 4][ni + 2], 0, 0, 0);
#pragma unroll
    for (int mi = 0; mi < 4; ++mi)
#pragma unroll
      for (int ni = 0; ni < 2; ++ni)
        acc[mi + 4][ni + 2] = __builtin_amdgcn_mfma_f32_16x16x32_bf16(af1[mi], bh1[ni], acc[mi + 4][ni + 2], 0, 0, 0);
    __builtin_amdgcn_s_setprio(0);
    __builtin_amdgcn_s_barrier();

    // ---------- phase 4: quadrant (mi 4-7, ni 0-1) -- 0 ds_reads + stage rest ----------
    if (p + 2 < npair) {
      STAGE_B(t1 + 4, 0); STAGE_B(t1 + 4, 1);
      STAGE_A(t0 + 4, 0); STAGE_A(t0 + 4, 1);   // A slots freed at ph3 barrier
      STAGE_A(t1 + 4, 0); STAGE_A(t1 + 4, 1);
    }
    __builtin_amdgcn_s_barrier();
    __builtin_amdgcn_s_setprio(1);
#pragma unroll
    for (int mi = 0; mi < 4; ++mi)
#pragma unroll
      for (int ni = 0; ni < 2; ++ni)
        acc[mi + 4][ni] = __builtin_amdgcn_mfma_f32_16x16x32_bf16(af0[mi], bg0[ni], acc[mi + 4][ni], 0, 0, 0);
#pragma unroll
    for (int mi = 0; mi < 4; ++mi)
#pragma unroll
      for (int ni = 0; ni < 2; ++ni)
        acc[mi + 4][ni] = __builtin_amdgcn_mfma_f32_16x16x32_bf16(af1[mi], bg1[ni], acc[mi + 4][ni], 0, 0, 0);
    __builtin_amdgcn_s_setprio(0);
    // no trailing barrier: loop-top vmcnt+barrier follows
  }
#undef SLOT
#undef STAGE_A
#undef STAGE_B
#undef DSR

  // epilogue: C/D layout col = lane&15, row = (lane>>4)*4 + reg  [verified m89/m91]
#pragma unroll
  for (int mi = 0; mi < 8; ++mi) {
#pragma unroll
    for (int ni = 0; ni < 4; ++ni) {
#pragma unroll
      for (int r = 0; r < 4; ++r) {
        const int row = bm0 + wr * 128 + mi * 16 + kq * 4 + r;
        const int col = bn0 + wc * 64 + ni * 16 + l15;
        const float v = acc[mi][ni][r];
        if constexpr (MODE == 2) {
          ((float*)Cv)[(size_t)blockIdx.z * cstride + (size_t)row * ldc + col] = v;
        } else {  // MODE 3: fused QKV
          unsigned short* q = (unsigned short*)Cv;
          if (col < 1024) {
            q[(size_t)row * 1024 + col] = f2bf(v);
          } else if (col < 2048) {
            q[16777216u + (size_t)row * 1024 + (col - 1024)] = f2bf(v);
          } else {
            const int b = row >> 11, s = row & 2047;
            q[33554432u + ((size_t)(b * 1024 + (col - 2048))) * 2048 + s] = f2bf(v);
          }
        }
      }
    }
  }
}

// ---------- row softmax over 2048 fp32 scores; writes bf16 P in-place (ld 4096) ----------
__global__ __launch_bounds__(256) void softmax_rows(float* __restrict__ scores) {
  float* base = scores + (size_t)blockIdx.y * 4194304 + (size_t)blockIdx.x * 2048;
  const int tid = threadIdx.x;
  const int wid = tid >> 6, lane = tid & 63;

  float v[8];
  float m = -1e30f;
#pragma unroll
  for (int i = 0; i < 8; ++i) {
    v[i] = base[tid + i * 256] * 0.03125f;  // 1/sqrt(1024)
    m = fmaxf(m, v[i]);
  }
  for (int off = 32; off; off >>= 1) m = fmaxf(m, __shfl_xor(m, off));
  __shared__ float redm[4], reds[4];
  if (lane == 0) redm[wid] = m;
  __syncthreads();            // all global reads of this row complete before here
  m = fmaxf(fmaxf(redm[0], redm[1]), fmaxf(redm[2], redm[3]));

  float s = 0.f;
#pragma unroll
  for (int i = 0; i < 8; ++i) { v[i] = expf(v[i] - m); s += v[i]; }
  for (int off = 32; off; off >>= 1) s += __shfl_xor(s, off);
  if (lane == 0) reds[wid] = s;
  __syncthreads();
  s = reds[0] + reds[1] + reds[2] + reds[3];
  const float inv = 1.0f / s;

  unsigned short* p = (unsigned short*)base;  // bf16 P, ld 4096, in-place (safe: writes after barrier)
#pragma unroll
  for (int i = 0; i < 8; ++i) p[tid + i * 256] = f2bf(v[i] * inv);
}

// ---------- launch ----------
extern "C" void kernel_launch(void* const* d_in, const int* in_sizes, int n_in,
                              void* d_out, int out_size, void* d_ws, size_t ws_size,
                              hipStream_t stream) {
  const float* x  = (const float*)d_in[0];
  const float* Wq = (const float*)d_in[1];
  const float* Wk = (const float*)d_in[2];
  const float* Wv = (const float*)d_in[3];
  float* out = (float*)d_out;
  char* ws = (char*)d_ws;

  // workspace layout (bytes)
  unsigned short* xb     = (unsigned short*)ws;                  // 33.5 MB
  unsigned short* wt_all = (unsigned short*)(ws + 33554432);     // 6 MB: WqT|WkT|WvT [3072][1024]
  unsigned short* qb     = (unsigned short*)(ws + 39845888);     // 33.5 MB
  unsigned short* kb     = qb + 16777216;                        // 33.5 MB
  unsigned short* vt     = kb + 16777216;                        // 33.5 MB (vT: [b*1024+e][s])
  const size_t off_scores = 140509184;                           // end of vt

  // scores scratch: 16 MiB per batch (2048 x 2048 fp32). Batch G at a time.
  int G; float* scores;
  if (ws_size >= off_scores + 8ull * 16777216) {
    G = 8; scores = (float*)(ws + off_scores);
  } else if (ws_size >= off_scores + 16777216) {
    size_t g = (ws_size - off_scores) / 16777216; G = (int)(g > 8 ? 8 : g);
    scores = (float*)(ws + off_scores);
  } else {
    G = 2; scores = (float*)ws;  // reuse xb region; xb dead after QKV
  }

  cast_f32_bf16<<<2048, 256, 0, stream>>>(x, xb, 16384 * 1024);
  transpose_cast_w<<<dim3(64, 64), 256, 0, stream>>>(Wq, wt_all);
  transpose_cast_w<<<dim3(64, 64), 256, 0, stream>>>(Wk, wt_all + 1048576);
  transpose_cast_w<<<dim3(64, 64), 256, 0, stream>>>(Wv, wt_all + 2097152);

  // fused QKV projection: M=16384, N=3072, K=1024 -> grid 12 x 64
  gemm256<3><<<dim3(12, 64), 512, 0, stream>>>(xb, 1024, 0, wt_all, 1024, 0,
                                               1024, qb, 0, 0);

  for (int b0 = 0; b0 < 8; b0 += G) {
    const int g = (8 - b0) < G ? (8 - b0) : G;
    const size_t so = (size_t)b0 * 2097152;  // q/k/v/out batch offset (elems)
    // scores = q·k^T (fp32): M=N=2048, K=1024, batched over z
    gemm256<2><<<dim3(8, 8, g), 512, 0, stream>>>(
        qb + so, 1024, 2097152, kb + so, 1024, 2097152, 1024,
        scores, 2048, 4194304);
    // softmax rows (applies 1/32 scale), P bf16 in-place at ld 4096
    softmax_rows<<<dim3(2048, g), 256, 0, stream>>>(scores);
    // out = P·v : A=P (lda 4096 ushort), B^T = vT_b [1024][2048], M=2048, N=1024, K=2048
    gemm256<2><<<dim3(4, 8, g), 512, 0, stream>>>(
        (const unsigned short*)scores, 4096, 8388608,
        vt + so, 2048, 2097152, 2048,
        out + so, 1024, 2097152);
  }
}

// Round 5
// 485.243 us; speedup vs baseline: 1.2865x; 1.2865x over previous
//
#include <hip/hip_runtime.h>
#include <hip/hip_bf16.h>

typedef __bf16 bf16x8 __attribute__((ext_vector_type(8)));
typedef float  f32x4  __attribute__((ext_vector_type(4)));

// ---------- helpers ----------
static __device__ __forceinline__ unsigned short f2bf(float f) {
  unsigned int u = __float_as_uint(f);
  u += 0x7FFFu + ((u >> 16) & 1u);   // round-to-nearest-even
  return (unsigned short)(u >> 16);
}

static __device__ __forceinline__ void gl_lds16(const void* g, void* l) {
  __builtin_amdgcn_global_load_lds(
      (const __attribute__((address_space(1))) void*)g,
      (__attribute__((address_space(3))) void*)l,
      16, 0, 0);
}

// ---------- cast x: f32 -> bf16 ----------
__global__ __launch_bounds__(256) void cast_f32_bf16(
    const float* __restrict__ in, unsigned short* __restrict__ out, int n) {
  int i = (blockIdx.x * 256 + threadIdx.x) * 4;
  const int stride = gridDim.x * 256 * 4;
  for (; i < n; i += stride) {
    float4 f = *(const float4*)(in + i);
    ushort4 o;
    o.x = f2bf(f.x); o.y = f2bf(f.y); o.z = f2bf(f.z); o.w = f2bf(f.w);
    *(ushort4*)(out + i) = o;
  }
}

// ---------- transpose-cast W (1024x1024): wt[n][k] = w[k][n], f32 -> bf16 ----------
__global__ __launch_bounds__(256) void transpose_cast_w(
    const float* __restrict__ w, unsigned short* __restrict__ wt) {
  __shared__ float tile[16][17];
  const int tx = threadIdx.x & 15, ty = threadIdx.x >> 4;
  const int bx = blockIdx.x * 16, by = blockIdx.y * 16;
  tile[ty][tx] = w[(size_t)(by + ty) * 1024 + bx + tx];
  __syncthreads();
  wt[(size_t)(bx + ty) * 1024 + by + tx] = f2bf(tile[tx][ty]);
}

// ---------- 256x256-tile bf16 MFMA GEMM, K-tile pairs (BK=64), counted vmcnt ----------
// B given transposed ([N][K]). 4 LDS slots of BK=32 (A 16KB | B 16KB each);
// pair p uses slots {2p&3,(2p+1)&3}. Slot layout: row-major [row 0..255][32 elem
// = 64 B]. Staging (r2-proven coalescing): thread chunk c = j*512+tid -> row
// c>>2, 16B sub-chunk c&3; each wave-load = 16 consecutive rows x 64 B
// CONTIGUOUS global memory (16 cache lines, 100% utilization) -- r3/r4's
// 64-line sliver gather was the 16%-MfmaUtil bottleneck. LDS dest is linear
// (wave-uniform base + lane*16). Fragment ds_read_b128 at row-stride 64 B:
// uniform 8 accesses/bank = BW minimum (no 128B-stride pathology).
// Per pair: 4 phases x {asm ds_reads | stage | s_barrier | lgkmcnt(0)+
// sched_barrier | setprio(1) 16 MFMA setprio(0) | s_barrier}. Reads 12/4/8/0.
// Stage pair p+2: ph3 = B(t0') (B freed at ph2 barrier), ph4 = B(t1')+A(both)
// (A freed at ph3 barrier). vmcnt(8) only at pair top (2 pairs in flight).
// All ds_reads inline asm (no mem clobber) so compiler can't alias them vs
// staging writes and insert vmcnt drains; manual waits + rule-#18 fences.
// MODE 2: C f32 [z*cstride + row*ldc + col]
// MODE 3: fused-QKV split write (Cv = qb base; kb = +16Mi elems, vt = +32Mi)
template <int MODE>
__global__ __launch_bounds__(512, 2) void gemm256(
    const unsigned short* __restrict__ A, int lda, size_t astride,
    const unsigned short* __restrict__ B, int ldb, size_t bstride,
    int K, void* __restrict__ Cv, int ldc, size_t cstride) {
  __shared__ __align__(16) unsigned char lds[131072];

  const unsigned d2 = blockIdx.x + gridDim.x * blockIdx.y;
  const unsigned ty = d2 % gridDim.y;
  const unsigned tx = d2 / gridDim.y;
  const int bm0 = ty * 256;
  const int bn0 = tx * 256;
  A += (size_t)blockIdx.z * astride;
  B += (size_t)blockIdx.z * bstride;

  const int tid = threadIdx.x;
  const int wid = tid >> 6, lane = tid & 63;
  const int wr = wid >> 2, wc = wid & 3;        // wave grid 2(M) x 4(N)
  const int l15 = lane & 15, kq = lane >> 4;

  // staging: chunk c = j*512 + tid -> row = c>>2 (64B rows), sub = (c&3)*16B
  const int srow0 = tid >> 2;
  const int scic  = (tid & 3) * 8;              // elem offset within row
  const size_t aoff0 = (size_t)(bm0 + srow0) * lda + scic;
  const size_t aoff1 = aoff0 + (size_t)128 * lda;
  const size_t boff0 = (size_t)(bn0 + srow0) * ldb + scic;
  const size_t boff1 = boff0 + (size_t)128 * ldb;
  const int dst0 = wid * 1024;                  // wave-uniform LDS byte offset (j=0)
  const int dst1 = 8192 + wid * 1024;           // j=1

  // LDS byte-address bases for asm ds_read_b128 (row-major, 64 B rows)
  const unsigned ldsbase =
      (unsigned)(unsigned long long)(__attribute__((address_space(3))) unsigned char*)lds;
  const unsigned aA = ldsbase + wr * 8192 + l15 * 64 + kq * 16;           // + mi*1024
  const unsigned aB = ldsbase + 16384 + wc * 4096 + l15 * 64 + kq * 16;   // + ni*1024

#define SLOT(t) ((unsigned)((t) & 3) * 32768u)
#define STAGE_A(t) do { unsigned char* s_ = lds + SLOT(t); \
    gl_lds16(A + aoff0 + (size_t)(t) * 32, s_ + dst0); \
    gl_lds16(A + aoff1 + (size_t)(t) * 32, s_ + dst1); } while (0)
#define STAGE_B(t) do { unsigned char* s_ = lds + SLOT(t) + 16384; \
    gl_lds16(B + boff0 + (size_t)(t) * 32, s_ + dst0); \
    gl_lds16(B + boff1 + (size_t)(t) * 32, s_ + dst1); } while (0)
#define DSR(dst, addr) asm volatile("ds_read_b128 %0, %1" : "=v"(dst) : "v"(addr))

  f32x4 acc[8][4] = {};
  bf16x8 af0[4], af1[4], bg0[2], bg1[2], bh0[2], bh1[2];

  const int npair = K >> 6;   // K % 64 == 0 here (1024 or 2048)
  // prologue: stage pairs 0 and 1 (slots 0-3; 16 wave-loads)
#pragma unroll
  for (int t = 0; t < 4; ++t) { STAGE_A(t); STAGE_B(t); }

  for (int p = 0; p < npair; ++p) {
    const int t0 = 2 * p, t1 = 2 * p + 1;
    const unsigned s0 = SLOT(t0), s1 = SLOT(t1);
    if (p < npair - 1) asm volatile("s_waitcnt vmcnt(8)" ::: "memory");
    else               asm volatile("s_waitcnt vmcnt(0)" ::: "memory");
    __builtin_amdgcn_s_barrier();   // all waves' pair-p stages landed

    // ---------- phase 1: quadrant (mi 0-3, ni 0-1) -- 12 ds_reads ----------
#pragma unroll
    for (int mi = 0; mi < 4; ++mi) DSR(af0[mi], s0 + aA + mi * 1024);
#pragma unroll
    for (int mi = 0; mi < 4; ++mi) DSR(af1[mi], s1 + aA + mi * 1024);
#pragma unroll
    for (int ni = 0; ni < 2; ++ni) { DSR(bg0[ni], s0 + aB + ni * 1024); DSR(bg1[ni], s1 + aB + ni * 1024); }
    asm volatile("s_waitcnt lgkmcnt(8)" ::: "memory");
    __builtin_amdgcn_s_barrier();
    asm volatile("s_waitcnt lgkmcnt(0)" ::: "memory");
    __builtin_amdgcn_sched_barrier(0);
    __builtin_amdgcn_s_setprio(1);
#pragma unroll
    for (int mi = 0; mi < 4; ++mi)
#pragma unroll
      for (int ni = 0; ni < 2; ++ni)
        acc[mi][ni] = __builtin_amdgcn_mfma_f32_16x16x32_bf16(af0[mi], bg0[ni], acc[mi][ni], 0, 0, 0);
#pragma unroll
    for (int mi = 0; mi < 4; ++mi)
#pragma unroll
      for (int ni = 0; ni < 2; ++ni)
        acc[mi][ni] = __builtin_amdgcn_mfma_f32_16x16x32_bf16(af1[mi], bg1[ni], acc[mi][ni], 0, 0, 0);
    __builtin_amdgcn_s_setprio(0);
    __builtin_amdgcn_s_barrier();

    // ---------- phase 2: quadrant (mi 0-3, ni 2-3) -- 4 ds_reads ----------
    DSR(bh0[0], s0 + aB + 2 * 1024); DSR(bh0[1], s0 + aB + 3 * 1024);
    DSR(bh1[0], s1 + aB + 2 * 1024); DSR(bh1[1], s1 + aB + 3 * 1024);
    __builtin_amdgcn_s_barrier();
    asm volatile("s_waitcnt lgkmcnt(0)" ::: "memory");
    __builtin_amdgcn_sched_barrier(0);
    __builtin_amdgcn_s_setprio(1);
#pragma unroll
    for (int mi = 0; mi < 4; ++mi)
#pragma unroll
      for (int ni = 0; ni < 2; ++ni)
        acc[mi][ni + 2] = __builtin_amdgcn_mfma_f32_16x16x32_bf16(af0[mi], bh0[ni], acc[mi][ni + 2], 0, 0, 0);
#pragma unroll
    for (int mi = 0; mi < 4; ++mi)
#pragma unroll
      for (int ni = 0; ni < 2; ++ni)
        acc[mi][ni + 2] = __builtin_amdgcn_mfma_f32_16x16x32_bf16(af1[mi], bh1[ni], acc[mi][ni + 2], 0, 0, 0);
    __builtin_amdgcn_s_setprio(0);
    __builtin_amdgcn_s_barrier();

    // ---------- phase 3: quadrant (mi 4-7, ni 2-3) -- 8 ds_reads + stage B' ----------
#pragma unroll
    for (int mi = 0; mi < 4; ++mi) DSR(af0[mi], s0 + aA + (mi + 4) * 1024);
#pragma unroll
    for (int mi = 0; mi < 4; ++mi) DSR(af1[mi], s1 + aA + (mi + 4) * 1024);
    if (p + 2 < npair) STAGE_B(t0 + 4);   // B region freed at ph2-end barrier
    __builtin_amdgcn_s_barrier();
    asm volatile("s_waitcnt lgkmcnt(0)" ::: "memory");
    __builtin_amdgcn_sched_barrier(0);
    __builtin_amdgcn_s_setprio(1);
#pragma unroll
    for (int mi = 0; mi < 4; ++mi)
#pragma unroll
      for (int ni = 0; ni < 2; ++ni)
        acc[mi + 4][ni + 2] = __builtin_amdgcn_mfma_f32_16x16x32_bf16(af0[mi], bh0[ni], acc[mi + 4][ni + 2], 0, 0, 0);
#pragma unroll
    for (int mi = 0; mi < 4; ++mi)
#pragma unroll
      for (int ni = 0; ni < 2; ++ni)
        acc[mi + 4][ni + 2] = __builtin_amdgcn_mfma_f32_16x16x32_bf16(af1[mi], bh1[ni], acc[mi + 4][ni + 2], 0, 0, 0);
    __builtin_amdgcn_s_setprio(0);
    __builtin_amdgcn_s_barrier();

    // ---------- phase 4: quadrant (mi 4-7, ni 0-1) -- 0 ds_reads + stage rest ----------
    if (p + 2 < npair) {
      STAGE_B(t1 + 4);
      STAGE_A(t0 + 4);                    // A regions freed at ph3-end barrier
      STAGE_A(t1 + 4);
    }
    __builtin_amdgcn_s_barrier();
    __builtin_amdgcn_s_setprio(1);
#pragma unroll
    for (int mi = 0; mi < 4; ++mi)
#pragma unroll
      for (int ni = 0; ni < 2; ++ni)
        acc[mi + 4][ni] = __builtin_amdgcn_mfma_f32_16x16x32_bf16(af0[mi], bg0[ni], acc[mi + 4][ni], 0, 0, 0);
#pragma unroll
    for (int mi = 0; mi < 4; ++mi)
#pragma unroll
      for (int ni = 0; ni < 2; ++ni)
        acc[mi + 4][ni] = __builtin_amdgcn_mfma_f32_16x16x32_bf16(af1[mi], bg1[ni], acc[mi + 4][ni], 0, 0, 0);
    __builtin_amdgcn_s_setprio(0);
    // no trailing barrier: loop-top vmcnt+barrier follows
  }
#undef SLOT
#undef STAGE_A
#undef STAGE_B
#undef DSR

  // epilogue: C/D layout col = lane&15, row = (lane>>4)*4 + reg  [verified m89/m91]
#pragma unroll
  for (int mi = 0; mi < 8; ++mi) {
#pragma unroll
    for (int ni = 0; ni < 4; ++ni) {
#pragma unroll
      for (int r = 0; r < 4; ++r) {
        const int row = bm0 + wr * 128 + mi * 16 + kq * 4 + r;
        const int col = bn0 + wc * 64 + ni * 16 + l15;
        const float v = acc[mi][ni][r];
        if constexpr (MODE == 2) {
          ((float*)Cv)[(size_t)blockIdx.z * cstride + (size_t)row * ldc + col] = v;
        } else {  // MODE 3: fused QKV
          unsigned short* q = (unsigned short*)Cv;
          if (col < 1024) {
            q[(size_t)row * 1024 + col] = f2bf(v);
          } else if (col < 2048) {
            q[16777216u + (size_t)row * 1024 + (col - 1024)] = f2bf(v);
          } else {
            const int b = row >> 11, s = row & 2047;
            q[33554432u + ((size_t)(b * 1024 + (col - 2048))) * 2048 + s] = f2bf(v);
          }
        }
      }
    }
  }
}

// ---------- row softmax over 2048 fp32 scores; writes bf16 P in-place (ld 4096) ----------
__global__ __launch_bounds__(256) void softmax_rows(float* __restrict__ scores) {
  float* base = scores + (size_t)blockIdx.y * 4194304 + (size_t)blockIdx.x * 2048;
  const int tid = threadIdx.x;
  const int wid = tid >> 6, lane = tid & 63;

  float v[8];
  float m = -1e30f;
#pragma unroll
  for (int i = 0; i < 8; ++i) {
    v[i] = base[tid + i * 256] * 0.03125f;  // 1/sqrt(1024)
    m = fmaxf(m, v[i]);
  }
  for (int off = 32; off; off >>= 1) m = fmaxf(m, __shfl_xor(m, off));
  __shared__ float redm[4], reds[4];
  if (lane == 0) redm[wid] = m;
  __syncthreads();            // all global reads of this row complete before here
  m = fmaxf(fmaxf(redm[0], redm[1]), fmaxf(redm[2], redm[3]));

  float s = 0.f;
#pragma unroll
  for (int i = 0; i < 8; ++i) { v[i] = expf(v[i] - m); s += v[i]; }
  for (int off = 32; off; off >>= 1) s += __shfl_xor(s, off);
  if (lane == 0) reds[wid] = s;
  __syncthreads();
  s = reds[0] + reds[1] + reds[2] + reds[3];
  const float inv = 1.0f / s;

  unsigned short* p = (unsigned short*)base;  // bf16 P, ld 4096, in-place (safe: writes after barrier)
#pragma unroll
  for (int i = 0; i < 8; ++i) p[tid + i * 256] = f2bf(v[i] * inv);
}

// ---------- launch ----------
extern "C" void kernel_launch(void* const* d_in, const int* in_sizes, int n_in,
                              void* d_out, int out_size, void* d_ws, size_t ws_size,
                              hipStream_t stream) {
  const float* x  = (const float*)d_in[0];
  const float* Wq = (const float*)d_in[1];
  const float* Wk = (const float*)d_in[2];
  const float* Wv = (const float*)d_in[3];
  float* out = (float*)d_out;
  char* ws = (char*)d_ws;

  // workspace layout (bytes)
  unsigned short* xb     = (unsigned short*)ws;                  // 33.5 MB
  unsigned short* wt_all = (unsigned short*)(ws + 33554432);     // 6 MB: WqT|WkT|WvT [3072][1024]
  unsigned short* qb     = (unsigned short*)(ws + 39845888);     // 33.5 MB
  unsigned short* kb     = qb + 16777216;                        // 33.5 MB
  unsigned short* vt     = kb + 16777216;                        // 33.5 MB (vT: [b*1024+e][s])
  const size_t off_scores = 140509184;                           // end of vt

  // scores scratch: 16 MiB per batch (2048 x 2048 fp32). Batch G at a time.
  int G; float* scores;
  if (ws_size >= off_scores + 8ull * 16777216) {
    G = 8; scores = (float*)(ws + off_scores);
  } else if (ws_size >= off_scores + 16777216) {
    size_t g = (ws_size - off_scores) / 16777216; G = (int)(g > 8 ? 8 : g);
    scores = (float*)(ws + off_scores);
  } else {
    G = 2; scores = (float*)ws;  // reuse xb region; xb dead after QKV
  }

  cast_f32_bf16<<<2048, 256, 0, stream>>>(x, xb, 16384 * 1024);
  transpose_cast_w<<<dim3(64, 64), 256, 0, stream>>>(Wq, wt_all);
  transpose_cast_w<<<dim3(64, 64), 256, 0, stream>>>(Wk, wt_all + 1048576);
  transpose_cast_w<<<dim3(64, 64), 256, 0, stream>>>(Wv, wt_all + 2097152);

  // fused QKV projection: M=16384, N=3072, K=1024 -> grid 12 x 64
  gemm256<3><<<dim3(12, 64), 512, 0, stream>>>(xb, 1024, 0, wt_all, 1024, 0,
                                               1024, qb, 0, 0);

  for (int b0 = 0; b0 < 8; b0 += G) {
    const int g = (8 - b0) < G ? (8 - b0) : G;
    const size_t so = (size_t)b0 * 2097152;  // q/k/v/out batch offset (elems)
    // scores = q·k^T (fp32): M=N=2048, K=1024, batched over z
    gemm256<2><<<dim3(8, 8, g), 512, 0, stream>>>(
        qb + so, 1024, 2097152, kb + so, 1024, 2097152, 1024,
        scores, 2048, 4194304);
    // softmax rows (applies 1/32 scale), P bf16 in-place at ld 4096
    softmax_rows<<<dim3(2048, g), 256, 0, stream>>>(scores);
    // out = P·v : A=P (lda 4096 ushort), B^T = vT_b [1024][2048], M=2048, N=1024, K=2048
    gemm256<2><<<dim3(4, 8, g), 512, 0, stream>>>(
        (const unsigned short*)scores, 4096, 8388608,
        vt + so, 2048, 2097152, 2048,
        out + so, 1024, 2097152);
  }
}

// Round 6
// 378.453 us; speedup vs baseline: 1.6495x; 1.2822x over previous
//
#include <hip/hip_runtime.h>
#include <hip/hip_bf16.h>

typedef __bf16 bf16x8 __attribute__((ext_vector_type(8)));
typedef float  f32x4  __attribute__((ext_vector_type(4)));

// ---------- helpers ----------
static __device__ __forceinline__ unsigned short f2bf(float f) {
  unsigned int u = __float_as_uint(f);
  u += 0x7FFFu + ((u >> 16) & 1u);   // round-to-nearest-even
  return (unsigned short)(u >> 16);
}

static __device__ __forceinline__ void gl_lds16(const void* g, void* l) {
  __builtin_amdgcn_global_load_lds(
      (const __attribute__((address_space(1))) void*)g,
      (__attribute__((address_space(3))) void*)l,
      16, 0, 0);
}

// ---------- cast x: f32 -> bf16 ----------
__global__ __launch_bounds__(256) void cast_f32_bf16(
    const float* __restrict__ in, unsigned short* __restrict__ out, int n) {
  int i = (blockIdx.x * 256 + threadIdx.x) * 4;
  const int stride = gridDim.x * 256 * 4;
  for (; i < n; i += stride) {
    float4 f = *(const float4*)(in + i);
    ushort4 o;
    o.x = f2bf(f.x); o.y = f2bf(f.y); o.z = f2bf(f.z); o.w = f2bf(f.w);
    *(ushort4*)(out + i) = o;
  }
}

// ---------- transpose-cast W (1024x1024): wt[n][k] = w[k][n], f32 -> bf16 ----------
__global__ __launch_bounds__(256) void transpose_cast_w(
    const float* __restrict__ w, unsigned short* __restrict__ wt) {
  __shared__ float tile[16][17];
  const int tx = threadIdx.x & 15, ty = threadIdx.x >> 4;
  const int bx = blockIdx.x * 16, by = blockIdx.y * 16;
  tile[ty][tx] = w[(size_t)(by + ty) * 1024 + bx + tx];
  __syncthreads();
  wt[(size_t)(bx + ty) * 1024 + by + tx] = f2bf(tile[tx][ty]);
}

// ---------- 128x128-tile bf16 MFMA GEMM (r2-proven structure), B transposed ----------
// XCD-locality remap: d2 -> (ty=d2%gy, tx=d2/gy); gy%8==0 keeps A-row-panel
// sharers on one XCD. blockIdx.z batches: A/B/C += z*stride.
// MODE 3: fused-QKV split write (Cv = qb base; kb = +16Mi elems, vt = +32Mi):
//   col<1024 -> q bf16 [row][col]; col<2048 -> k bf16 [row][col-1024];
//   col>=2048 -> vT bf16 [(b*1024+col-2048)*2048 + s], b=row>>11, s=row&2047
// MODE 4: scores with fused exp + partial row-sums (softmax-free pipeline):
//   P'[z*cstride + row*ldc + col] = bf16(exp(acc/32)); per-block 128-col row
//   sums -> aux[(z*16 + tx)*2048 + bm0 + r] (deterministic per-block slots).
// MODE 5: PV with row rescale: C f32 = acc * aux[z*2048 + row].
template <int MODE>
__global__ __launch_bounds__(256, 2) void gemm_bt(
    const unsigned short* __restrict__ A, int lda, size_t astride,
    const unsigned short* __restrict__ B, int ldb, size_t bstride,
    int K, void* __restrict__ Cv, int ldc, size_t cstride,
    float* __restrict__ aux) {
  __shared__ __align__(16) unsigned char lds[16384];  // A tile 8KB | B tile 8KB
  const unsigned d2 = blockIdx.x + gridDim.x * blockIdx.y;
  const unsigned ty = d2 % gridDim.y;
  const unsigned tx = d2 / gridDim.y;
  const int bn0 = tx * 128;
  const int bm0 = ty * 128;
  A += (size_t)blockIdx.z * astride;
  B += (size_t)blockIdx.z * bstride;

  const int tid = threadIdx.x;
  const int wid = tid >> 6, lane = tid & 63;
  const int wr = wid >> 1, wc = wid & 1;
  const int l15 = lane & 15, kq = lane >> 4;

  // staging: element e = wid*512 + lane*8 -> (row e>>5, col e&31)
  const int e0 = wid * 512 + lane * 8;
  const int r0 = e0 >> 5, c0 = e0 & 31;
  const size_t aoff0 = (size_t)(bm0 + r0) * lda + c0;
  const size_t aoff1 = (size_t)(bm0 + r0 + 64) * lda + c0;
  const size_t boff0 = (size_t)(bn0 + r0) * ldb + c0;
  const size_t boff1 = (size_t)(bn0 + r0 + 64) * ldb + c0;
  unsigned char* ldsA = lds + wid * 1024;         // wave-uniform base
  unsigned char* ldsB = lds + 8192 + wid * 1024;

  f32x4 acc[4][4] = {};
  const int nkt = K >> 5;
  for (int kt = 0; kt < nkt; ++kt) {
    const int kc = kt << 5;
    gl_lds16(A + aoff0 + kc, ldsA);
    gl_lds16(A + aoff1 + kc, ldsA + 4096);
    gl_lds16(B + boff0 + kc, ldsB);
    gl_lds16(B + boff1 + kc, ldsB + 4096);
    __syncthreads();   // compiler drains vmcnt before s_barrier

    bf16x8 af[4], bg[4];
#pragma unroll
    for (int mi = 0; mi < 4; ++mi)
      af[mi] = *(const bf16x8*)(lds + ((wr * 64 + mi * 16 + l15) * 64 + kq * 16));
#pragma unroll
    for (int ni = 0; ni < 4; ++ni)
      bg[ni] = *(const bf16x8*)(lds + 8192 + ((wc * 64 + ni * 16 + l15) * 64 + kq * 16));
#pragma unroll
    for (int mi = 0; mi < 4; ++mi)
#pragma unroll
      for (int ni = 0; ni < 4; ++ni)
        acc[mi][ni] = __builtin_amdgcn_mfma_f32_16x16x32_bf16(af[mi], bg[ni], acc[mi][ni], 0, 0, 0);
    __syncthreads();
  }

  // epilogue: C/D layout col = lane&15, row = (lane>>4)*4 + reg  [verified m89/m91]
  if constexpr (MODE == 3) {
#pragma unroll
    for (int mi = 0; mi < 4; ++mi)
#pragma unroll
      for (int ni = 0; ni < 4; ++ni)
#pragma unroll
        for (int r = 0; r < 4; ++r) {
          const int row = bm0 + wr * 64 + mi * 16 + kq * 4 + r;
          const int col = bn0 + wc * 64 + ni * 16 + l15;
          const float v = acc[mi][ni][r];
          unsigned short* q = (unsigned short*)Cv;
          if (col < 1024) {
            q[(size_t)row * 1024 + col] = f2bf(v);
          } else if (col < 2048) {
            q[16777216u + (size_t)row * 1024 + (col - 1024)] = f2bf(v);
          } else {
            const int b = row >> 11, s = row & 2047;
            q[33554432u + ((size_t)(b * 1024 + (col - 2048))) * 2048 + s] = f2bf(v);
          }
        }
  } else if constexpr (MODE == 4) {
    __shared__ float redsm[128][2];
    unsigned short* pp = (unsigned short*)Cv + (size_t)blockIdx.z * cstride;
    float rs[4][4];
#pragma unroll
    for (int mi = 0; mi < 4; ++mi)
#pragma unroll
      for (int r = 0; r < 4; ++r) rs[mi][r] = 0.f;
#pragma unroll
    for (int mi = 0; mi < 4; ++mi)
#pragma unroll
      for (int ni = 0; ni < 4; ++ni)
#pragma unroll
        for (int r = 0; r < 4; ++r) {
          // exp(acc/32) = 2^(acc * log2(e)/32)
          const float e = exp2f(acc[mi][ni][r] * 0.045084220027780106f);
          rs[mi][r] += e;
          const int row = bm0 + wr * 64 + mi * 16 + kq * 4 + r;
          const int col = bn0 + wc * 64 + ni * 16 + l15;
          pp[(size_t)row * ldc + col] = f2bf(e);
        }
    // reduce each row's 64-col wave partial over the 16 l15 lanes
#pragma unroll
    for (int mi = 0; mi < 4; ++mi)
#pragma unroll
      for (int r = 0; r < 4; ++r) {
        float s = rs[mi][r];
        s += __shfl_xor(s, 1); s += __shfl_xor(s, 2);
        s += __shfl_xor(s, 4); s += __shfl_xor(s, 8);
        rs[mi][r] = s;
      }
    if (l15 == 0) {
#pragma unroll
      for (int mi = 0; mi < 4; ++mi)
#pragma unroll
        for (int r = 0; r < 4; ++r)
          redsm[wr * 64 + mi * 16 + kq * 4 + r][wc] = rs[mi][r];
    }
    __syncthreads();
    if (tid < 128)
      aux[((size_t)blockIdx.z * 16 + tx) * 2048 + bm0 + tid] =
          redsm[tid][0] + redsm[tid][1];
  } else {  // MODE 5
    const float* inv = aux + (size_t)blockIdx.z * 2048;
    float* op = (float*)Cv + (size_t)blockIdx.z * cstride;
#pragma unroll
    for (int mi = 0; mi < 4; ++mi)
#pragma unroll
      for (int r = 0; r < 4; ++r) {
        const int row = bm0 + wr * 64 + mi * 16 + kq * 4 + r;
        const float iv = inv[row];
#pragma unroll
        for (int ni = 0; ni < 4; ++ni) {
          const int col = bn0 + wc * 64 + ni * 16 + l15;
          op[(size_t)row * ldc + col] = acc[mi][ni][r] * iv;
        }
      }
  }
}

// ---------- combine partial row-sums -> inv[row] (deterministic order) ----------
__global__ __launch_bounds__(256) void combine_inv(
    const float* __restrict__ part, float* __restrict__ inv, int n) {
  const int i = blockIdx.x * 256 + threadIdx.x;
  if (i >= n) return;            // n = g*2048
  const int z = i >> 11, row = i & 2047;
  const float* p = part + ((size_t)z * 16) * 2048 + row;
  float s = 0.f;
#pragma unroll
  for (int j = 0; j < 16; ++j) s += p[j * 2048];
  inv[i] = 1.0f / s;
}

// ---------- launch ----------
extern "C" void kernel_launch(void* const* d_in, const int* in_sizes, int n_in,
                              void* d_out, int out_size, void* d_ws, size_t ws_size,
                              hipStream_t stream) {
  const float* x  = (const float*)d_in[0];
  const float* Wq = (const float*)d_in[1];
  const float* Wk = (const float*)d_in[2];
  const float* Wv = (const float*)d_in[3];
  float* out = (float*)d_out;
  char* ws = (char*)d_ws;

  // workspace layout (bytes)
  unsigned short* xb     = (unsigned short*)ws;                  // 33.5 MB (dead after QKV)
  unsigned short* wt_all = (unsigned short*)(ws + 33554432);     // 6 MB: WqT|WkT|WvT [3072][1024]
  unsigned short* qb     = (unsigned short*)(ws + 39845888);     // 33.5 MB
  unsigned short* kb     = qb + 16777216;                        // 33.5 MB
  unsigned short* vt     = kb + 16777216;                        // 33.5 MB (vT: [b*1024+e][s])
  const size_t off_scores = 140509184ull;                        // end of vt

  // per-batch attention scratch: P' bf16 8 MiB + part 128 KiB + inv 8 KiB
  const size_t per_b = 8388608ull + 131072ull + 8192ull;
  int G; char *pPc, *partc, *invc;
  const size_t avail = ws_size > off_scores ? ws_size - off_scores : 0;
  G = (int)(avail / per_b); if (G > 8) G = 8;
  if (G >= 1) {
    pPc   = ws + off_scores;
    partc = pPc + (size_t)G * 8388608ull;
    invc  = partc + (size_t)G * 131072ull;
  } else {
    G = 2;  // fallback: reuse xb region (33.5 MB >= 2 x 8.53 MB); xb dead after QKV
    pPc   = ws;
    partc = ws + 2 * 8388608ull;
    invc  = partc + 2 * 131072ull;
  }

  cast_f32_bf16<<<2048, 256, 0, stream>>>(x, xb, 16384 * 1024);
  transpose_cast_w<<<dim3(64, 64), 256, 0, stream>>>(Wq, wt_all);
  transpose_cast_w<<<dim3(64, 64), 256, 0, stream>>>(Wk, wt_all + 1048576);
  transpose_cast_w<<<dim3(64, 64), 256, 0, stream>>>(Wv, wt_all + 2097152);

  // fused QKV projection: M=16384, N=3072, K=1024
  gemm_bt<3><<<dim3(24, 128), 256, 0, stream>>>(xb, 1024, 0, wt_all, 1024, 0,
                                                1024, qb, 0, 0, nullptr);

  for (int b0 = 0; b0 < 8; b0 += G) {
    const int g = (8 - b0) < G ? (8 - b0) : G;
    const size_t so = (size_t)b0 * 2097152;  // q/k/v/out batch offset (elems)
    // P' = exp(q.k^T/32) bf16 + partial row sums: M=N=2048, K=1024
    gemm_bt<4><<<dim3(16, 16, g), 256, 0, stream>>>(
        qb + so, 1024, 2097152, kb + so, 1024, 2097152, 1024,
        (unsigned short*)pPc, 2048, 4194304, (float*)partc);
    // inv[row] = 1 / sum_row  (deterministic 16-partial combine)
    combine_inv<<<(g * 2048 + 255) / 256, 256, 0, stream>>>(
        (const float*)partc, (float*)invc, g * 2048);
    // out = (P'.v) * inv : A=P' [2048][2048] bf16, B^T = vT_b [1024][2048], K=2048
    gemm_bt<5><<<dim3(8, 16, g), 256, 0, stream>>>(
        (const unsigned short*)pPc, 2048, 4194304,
        vt + so, 2048, 2097152, 2048,
        out + so, 1024, 2097152, (float*)invc);
  }
}

// Round 7
// 346.208 us; speedup vs baseline: 1.8031x; 1.0931x over previous
//
#include <hip/hip_runtime.h>
#include <hip/hip_bf16.h>

typedef __bf16 bf16x8 __attribute__((ext_vector_type(8)));
typedef float  f32x4  __attribute__((ext_vector_type(4)));

// ---------- helpers ----------
static __device__ __forceinline__ unsigned short f2bf(float f) {
  unsigned int u = __float_as_uint(f);
  u += 0x7FFFu + ((u >> 16) & 1u);   // round-to-nearest-even
  return (unsigned short)(u >> 16);
}

static __device__ __forceinline__ void gl_lds16(const void* g, void* l) {
  __builtin_amdgcn_global_load_lds(
      (const __attribute__((address_space(1))) void*)g,
      (__attribute__((address_space(3))) void*)l,
      16, 0, 0);
}

// ---------- cast x: f32 -> bf16 ----------
__global__ __launch_bounds__(256) void cast_f32_bf16(
    const float* __restrict__ in, unsigned short* __restrict__ out, int n) {
  int i = (blockIdx.x * 256 + threadIdx.x) * 4;
  const int stride = gridDim.x * 256 * 4;
  for (; i < n; i += stride) {
    float4 f = *(const float4*)(in + i);
    ushort4 o;
    o.x = f2bf(f.x); o.y = f2bf(f.y); o.z = f2bf(f.z); o.w = f2bf(f.w);
    *(ushort4*)(out + i) = o;
  }
}

// ---------- transpose-cast W (1024x1024): wt[n][k] = w[k][n], f32 -> bf16 ----------
__global__ __launch_bounds__(256) void transpose_cast_w(
    const float* __restrict__ w, unsigned short* __restrict__ wt) {
  __shared__ float tile[16][17];
  const int tx = threadIdx.x & 15, ty = threadIdx.x >> 4;
  const int bx = blockIdx.x * 16, by = blockIdx.y * 16;
  tile[ty][tx] = w[(size_t)(by + ty) * 1024 + bx + tx];
  __syncthreads();
  wt[(size_t)(bx + ty) * 1024 + by + tx] = f2bf(tile[tx][ty]);
}

// ---------- 128x128-tile bf16 MFMA GEMM, BK=64 (two stacked r2 sub-tiles) ----------
// B given transposed ([N][K]). XCD-locality remap: d2 -> (ty=d2%gy, tx=d2/gy);
// gy%8==0 keeps A-row-panel sharers on one XCD. blockIdx.z batches.
// LDS 32 KiB: A 16 KiB as [kk 0..1][row 0..127][32 elem = 64 B], B same.
// Sub-K-major keeps BOTH r2-proven properties: staging = 16 rows x 64 B
// contiguous per wave-load (16 full cache lines) and 64 B row stride on
// ds_read_b128 (conflict-neutral, measured ~0 in r2). One barrier-pair per
// 64 K (2x fewer drains than r2's BK=32 -- the 25%-MfmaUtil limiter).
// MODE 3: fused-QKV split write (Cv = qb base; kb = +16Mi elems, vt = +32Mi):
//   col<1024 -> q bf16 [row][col]; col<2048 -> k bf16 [row][col-1024];
//   col>=2048 -> vT bf16 [(b*1024+col-2048)*2048 + s], b=row>>11, s=row&2047
// MODE 4: scores with fused exp + partial row-sums (softmax-free pipeline):
//   P'[z*cstride + row*ldc + col] = bf16(exp(acc/32)); per-block 128-col row
//   sums -> aux[(z*16 + tx)*2048 + bm0 + r] (deterministic per-block slots).
// MODE 5: PV with row rescale: C f32 = acc * aux[z*2048 + row].
template <int MODE>
__global__ __launch_bounds__(256, 2) void gemm_bt(
    const unsigned short* __restrict__ A, int lda, size_t astride,
    const unsigned short* __restrict__ B, int ldb, size_t bstride,
    int K, void* __restrict__ Cv, int ldc, size_t cstride,
    float* __restrict__ aux) {
  __shared__ __align__(16) unsigned char lds[32768];  // A 16KB | B 16KB
  const unsigned d2 = blockIdx.x + gridDim.x * blockIdx.y;
  const unsigned ty = d2 % gridDim.y;
  const unsigned tx = d2 / gridDim.y;
  const int bn0 = tx * 128;
  const int bm0 = ty * 128;
  A += (size_t)blockIdx.z * astride;
  B += (size_t)blockIdx.z * bstride;

  const int tid = threadIdx.x;
  const int wid = tid >> 6, lane = tid & 63;
  const int wr = wid >> 1, wc = wid & 1;
  const int l15 = lane & 15, kq = lane >> 4;

  // staging: chunk c = j*256 + tid -> kk = j>>1, row = (j&1)*64 + tid>>2,
  // sub-16B = tid&3. LDS dest byte = c*16 (linear, wave-uniform base + lane*16).
  const int sr = tid >> 2;
  const int ssub = (tid & 3) * 8;
  size_t aoff[4], boff[4];
#pragma unroll
  for (int j = 0; j < 4; ++j) {
    const int r = (j & 1) * 64 + sr;
    const int kko = (j >> 1) * 32;
    aoff[j] = (size_t)(bm0 + r) * lda + kko + ssub;
    boff[j] = (size_t)(bn0 + r) * ldb + kko + ssub;
  }
  unsigned char* dstA = lds + wid * 1024;           // + j*4096
  unsigned char* dstB = lds + 16384 + wid * 1024;   // + j*4096

  f32x4 acc[4][4] = {};
  const int nkt = K >> 6;
  for (int kt = 0; kt < nkt; ++kt) {
    const int kc = kt << 6;
#pragma unroll
    for (int j = 0; j < 4; ++j) {
      gl_lds16(A + aoff[j] + kc, dstA + j * 4096);
      gl_lds16(B + boff[j] + kc, dstB + j * 4096);
    }
    __syncthreads();   // compiler drains vmcnt before s_barrier

#pragma unroll
    for (int kk = 0; kk < 2; ++kk) {
      bf16x8 af[4], bg[4];
#pragma unroll
      for (int mi = 0; mi < 4; ++mi)
        af[mi] = *(const bf16x8*)(lds + kk * 8192 + (wr * 64 + mi * 16 + l15) * 64 + kq * 16);
#pragma unroll
      for (int ni = 0; ni < 4; ++ni)
        bg[ni] = *(const bf16x8*)(lds + 16384 + kk * 8192 + (wc * 64 + ni * 16 + l15) * 64 + kq * 16);
#pragma unroll
      for (int mi = 0; mi < 4; ++mi)
#pragma unroll
        for (int ni = 0; ni < 4; ++ni)
          acc[mi][ni] = __builtin_amdgcn_mfma_f32_16x16x32_bf16(af[mi], bg[ni], acc[mi][ni], 0, 0, 0);
    }
    __syncthreads();
  }

  // epilogue: C/D layout col = lane&15, row = (lane>>4)*4 + reg  [verified m89/m91]
  if constexpr (MODE == 3) {
#pragma unroll
    for (int mi = 0; mi < 4; ++mi)
#pragma unroll
      for (int ni = 0; ni < 4; ++ni)
#pragma unroll
        for (int r = 0; r < 4; ++r) {
          const int row = bm0 + wr * 64 + mi * 16 + kq * 4 + r;
          const int col = bn0 + wc * 64 + ni * 16 + l15;
          const float v = acc[mi][ni][r];
          unsigned short* q = (unsigned short*)Cv;
          if (col < 1024) {
            q[(size_t)row * 1024 + col] = f2bf(v);
          } else if (col < 2048) {
            q[16777216u + (size_t)row * 1024 + (col - 1024)] = f2bf(v);
          } else {
            const int b = row >> 11, s = row & 2047;
            q[33554432u + ((size_t)(b * 1024 + (col - 2048))) * 2048 + s] = f2bf(v);
          }
        }
  } else if constexpr (MODE == 4) {
    __shared__ float redsm[128][2];
    unsigned short* pp = (unsigned short*)Cv + (size_t)blockIdx.z * cstride;
    float rs[4][4];
#pragma unroll
    for (int mi = 0; mi < 4; ++mi)
#pragma unroll
      for (int r = 0; r < 4; ++r) rs[mi][r] = 0.f;
#pragma unroll
    for (int mi = 0; mi < 4; ++mi)
#pragma unroll
      for (int ni = 0; ni < 4; ++ni)
#pragma unroll
        for (int r = 0; r < 4; ++r) {
          // exp(acc/32) = 2^(acc * log2(e)/32)
          const float e = exp2f(acc[mi][ni][r] * 0.045084220027780106f);
          rs[mi][r] += e;
          const int row = bm0 + wr * 64 + mi * 16 + kq * 4 + r;
          const int col = bn0 + wc * 64 + ni * 16 + l15;
          pp[(size_t)row * ldc + col] = f2bf(e);
        }
    // reduce each row's 64-col wave partial over the 16 l15 lanes
#pragma unroll
    for (int mi = 0; mi < 4; ++mi)
#pragma unroll
      for (int r = 0; r < 4; ++r) {
        float s = rs[mi][r];
        s += __shfl_xor(s, 1); s += __shfl_xor(s, 2);
        s += __shfl_xor(s, 4); s += __shfl_xor(s, 8);
        rs[mi][r] = s;
      }
    if (l15 == 0) {
#pragma unroll
      for (int mi = 0; mi < 4; ++mi)
#pragma unroll
        for (int r = 0; r < 4; ++r)
          redsm[wr * 64 + mi * 16 + kq * 4 + r][wc] = rs[mi][r];
    }
    __syncthreads();
    if (tid < 128)
      aux[((size_t)blockIdx.z * 16 + tx) * 2048 + bm0 + tid] =
          redsm[tid][0] + redsm[tid][1];
  } else {  // MODE 5
    const float* inv = aux + (size_t)blockIdx.z * 2048;
    float* op = (float*)Cv + (size_t)blockIdx.z * cstride;
#pragma unroll
    for (int mi = 0; mi < 4; ++mi)
#pragma unroll
      for (int r = 0; r < 4; ++r) {
        const int row = bm0 + wr * 64 + mi * 16 + kq * 4 + r;
        const float iv = inv[row];
#pragma unroll
        for (int ni = 0; ni < 4; ++ni) {
          const int col = bn0 + wc * 64 + ni * 16 + l15;
          op[(size_t)row * ldc + col] = acc[mi][ni][r] * iv;
        }
      }
  }
}

// ---------- combine partial row-sums -> inv[row] (deterministic order) ----------
__global__ __launch_bounds__(256) void combine_inv(
    const float* __restrict__ part, float* __restrict__ inv, int n) {
  const int i = blockIdx.x * 256 + threadIdx.x;
  if (i >= n) return;            // n = g*2048
  const int z = i >> 11, row = i & 2047;
  const float* p = part + ((size_t)z * 16) * 2048 + row;
  float s = 0.f;
#pragma unroll
  for (int j = 0; j < 16; ++j) s += p[j * 2048];
  inv[i] = 1.0f / s;
}

// ---------- launch ----------
extern "C" void kernel_launch(void* const* d_in, const int* in_sizes, int n_in,
                              void* d_out, int out_size, void* d_ws, size_t ws_size,
                              hipStream_t stream) {
  const float* x  = (const float*)d_in[0];
  const float* Wq = (const float*)d_in[1];
  const float* Wk = (const float*)d_in[2];
  const float* Wv = (const float*)d_in[3];
  float* out = (float*)d_out;
  char* ws = (char*)d_ws;

  // workspace layout (bytes)
  unsigned short* xb     = (unsigned short*)ws;                  // 33.5 MB (dead after QKV)
  unsigned short* wt_all = (unsigned short*)(ws + 33554432);     // 6 MB: WqT|WkT|WvT [3072][1024]
  unsigned short* qb     = (unsigned short*)(ws + 39845888);     // 33.5 MB
  unsigned short* kb     = qb + 16777216;                        // 33.5 MB
  unsigned short* vt     = kb + 16777216;                        // 33.5 MB (vT: [b*1024+e][s])
  const size_t off_scores = 140509184ull;                        // end of vt

  // per-batch attention scratch: P' bf16 8 MiB + part 128 KiB + inv 8 KiB
  const size_t per_b = 8388608ull + 131072ull + 8192ull;
  int G; char *pPc, *partc, *invc;
  const size_t avail = ws_size > off_scores ? ws_size - off_scores : 0;
  G = (int)(avail / per_b); if (G > 8) G = 8;
  if (G >= 1) {
    pPc   = ws + off_scores;
    partc = pPc + (size_t)G * 8388608ull;
    invc  = partc + (size_t)G * 131072ull;
  } else {
    G = 2;  // fallback: reuse xb region (33.5 MB >= 2 x 8.53 MB); xb dead after QKV
    pPc   = ws;
    partc = ws + 2 * 8388608ull;
    invc  = partc + 2 * 131072ull;
  }

  cast_f32_bf16<<<2048, 256, 0, stream>>>(x, xb, 16384 * 1024);
  transpose_cast_w<<<dim3(64, 64), 256, 0, stream>>>(Wq, wt_all);
  transpose_cast_w<<<dim3(64, 64), 256, 0, stream>>>(Wk, wt_all + 1048576);
  transpose_cast_w<<<dim3(64, 64), 256, 0, stream>>>(Wv, wt_all + 2097152);

  // fused QKV projection: M=16384, N=3072, K=1024
  gemm_bt<3><<<dim3(24, 128), 256, 0, stream>>>(xb, 1024, 0, wt_all, 1024, 0,
                                                1024, qb, 0, 0, nullptr);

  for (int b0 = 0; b0 < 8; b0 += G) {
    const int g = (8 - b0) < G ? (8 - b0) : G;
    const size_t so = (size_t)b0 * 2097152;  // q/k/v/out batch offset (elems)
    // P' = exp(q.k^T/32) bf16 + partial row sums: M=N=2048, K=1024
    gemm_bt<4><<<dim3(16, 16, g), 256, 0, stream>>>(
        qb + so, 1024, 2097152, kb + so, 1024, 2097152, 1024,
        (unsigned short*)pPc, 2048, 4194304, (float*)partc);
    // inv[row] = 1 / sum_row  (deterministic 16-partial combine)
    combine_inv<<<(g * 2048 + 255) / 256, 256, 0, stream>>>(
        (const float*)partc, (float*)invc, g * 2048);
    // out = (P'.v) * inv : A=P' [2048][2048] bf16, B^T = vT_b [1024][2048], K=2048
    gemm_bt<5><<<dim3(8, 16, g), 256, 0, stream>>>(
        (const unsigned short*)pPc, 2048, 4194304,
        vt + so, 2048, 2097152, 2048,
        out + so, 1024, 2097152, (float*)invc);
  }
}